// Round 12
// baseline (12025.344 us; speedup 1.0000x reference)
//
#include <hip/hip_runtime.h>

#define TT 800

typedef __attribute__((ext_vector_type(8))) short bf16x8;
typedef __attribute__((ext_vector_type(4))) float f32x4;
typedef unsigned short u16;
typedef unsigned int u32;
typedef unsigned long long u64;

constexpr int NWG = 136;
constexpr size_t WL0A_OFF = 0;              // [2048][512] bf16 (W_hh0, K-major)
constexpr size_t WL0B_OFF = 2097152;        // [128][2048] bf16 (W_ih0^T row-gather)
constexpr size_t WL1_OFF  = 2621440;        // [2048][1024] bf16
constexpr size_t WLIN_OFF = 6815744;        // [128][512] bf16
constexpr size_t H0_OFF   = 6946816;        // [2][256][512] bf16
constexpr size_t H1_OFF   = 7471104;        // [2][256][512] bf16
constexpr size_t BAR_OFF  = 7995392;        // flags + handshake (2KB memset)
constexpr int HB = 256 * 512;
// ROUND-12 LDS: per-chain half-size buffers; total unchanged (<64K).
//   AA (chain A h) 16 x 520 u16 = 16640 @ 0
//   AB (chain B h) 16 x 520 u16 = 16640 @ 16640
//   GfA 16 x 129 f32 = 8256 @ 33280
//   GfB 16 x 129 f32 = 8256 @ 41536
//   P (softmax) 3 x 256 f32 = 3072 @ 49792   -> 52864
constexpr int A_ST = 520;
constexpr int AB_OFF_B = 16640;
constexpr int GA_OFF_B = 33280;
constexpr int GB_OFF_B = 41536;
constexpr int P_OFF_B  = 49792;
constexpr int LDS_BYTES = 53248;

__device__ __forceinline__ u16 f2b(float x) {
  u32 u = __float_as_uint(x);
  return (u16)((u + 0x7FFFu + ((u >> 16) & 1u)) >> 16);   // RNE fp32->bf16
}
__device__ __forceinline__ float b2f(u16 v) { return __uint_as_float(((u32)v) << 16); }
__device__ __forceinline__ float sigf(float x) { return 1.f / (1.f + __expf(-x)); }
__device__ __forceinline__ float tanh_f(float x) { float e = __expf(2.f * x); return 1.f - 2.f / (e + 1.f); }

// ---- agent-scope (cross-XCD safe) data ops: fallback path ----
__device__ __forceinline__ u64 ld_coh8(const u64* p) {
  return __hip_atomic_load(p, __ATOMIC_RELAXED, __HIP_MEMORY_SCOPE_AGENT);
}
__device__ __forceinline__ void st_coh8(u64* p, u64 v) {
  __hip_atomic_store(p, v, __ATOMIC_RELAXED, __HIP_MEMORY_SCOPE_AGENT);
}
__device__ __forceinline__ void st_coh4(u32* p, u32 v) {
  __hip_atomic_store(p, v, __ATOMIC_RELAXED, __HIP_MEMORY_SCOPE_AGENT);
}
// ---- ROUND-12: TWO INDEPENDENT 16-ROW CHAINS PER TILE, INTERLEAVED.
// Champion analysis: ~6us of the 9.4us tick is wait; the largest
// unattacked term is the producer-post -> consumer-detect round trip
// (post store ~200cy to L2, poll load ~200-300cy + detect granularity),
// serialized into every tick because nothing else can execute during it.
// Fix: split each tile's 32 batch rows into chains A (rows 0..15) and
// B (rows 16..31) — fully independent recurrences sharing the same 17
// WGs and the SAME weight registers (slices are unit-ranges). Each loop
// iteration runs tick tau of A then tick tau of B. When the WG polls
// A(tau+1), the A(tau) posts happened BEFORE it ran B(tau)'s whole
// phase -> post->detect RT hides under the other chain's work; polls
// degenerate to one satisfied L2 read. Per-chain memory semantics are
// byte-for-byte round-9: plain loads + l1inv per chain phase (lok),
// plain write-through stores, per-WG flag words (r11 proved agent loads
// lose L1 pair-coalescing; r4 proved swap-stores worse; r10 proved
// multi-wave inv polling worse — wave-0 polls only).
// Flags: per tile 48 u32 words: A slots 0..16, B slots 20..36.
__device__ __forceinline__ void fpost_l(u32* fw, u32 v) { *(volatile u32*)fw = v; }
__device__ __forceinline__ void fpost_a(u32* fw, u32 v) {
  __hip_atomic_store(fw, v, __ATOMIC_RELAXED, __HIP_MEMORY_SCOPE_AGENT);
}
__device__ __forceinline__ void wave_poll(u32* Fw, int lane, u32 thr, bool lok) {
  int idx = (lane < 17) ? lane : 16;
  if (lok) {
    while (true) {
      u32 v = *(volatile u32*)(Fw + idx);
      if (__all((int)(v >= thr))) break;
      asm volatile("buffer_inv" ::: "memory");
    }
  } else {
    while (true) {
      u32 v = __hip_atomic_load(Fw + idx, __ATOMIC_RELAXED, __HIP_MEMORY_SCOPE_AGENT);
      if (__all((int)(v >= thr))) break;
      __builtin_amdgcn_s_sleep(1);
    }
  }
}
__device__ __forceinline__ void l1inv() { asm volatile("buffer_inv" ::: "memory"); }

__global__ void prep_kernel(const float* __restrict__ wih0, const float* __restrict__ whh0,
                            const float* __restrict__ wih1, const float* __restrict__ whh1,
                            const float* __restrict__ wlinf,
                            u16* __restrict__ wl0a, u16* __restrict__ wl0b,
                            u16* __restrict__ wl1, u16* __restrict__ wlin) {
  int i = blockIdx.x * 256 + threadIdx.x;
  const int NA = 2048 * 512, NB = 128 * 2048, N1 = 2048 * 1024, N2 = 128 * 512;
  if (i < NA) {
    int col = i >> 9, k = i & 511;
    wl0a[i] = f2b(whh0[col * 512 + k]);
  } else if (i < NA + NB) {
    int j = i - NA, k = j >> 11, col = j & 2047;
    wl0b[j] = f2b(wih0[col * 128 + k]);
  } else if (i < NA + NB + N1) {
    int j = i - NA - NB, col = j >> 10, k = j & 1023;
    float v = (k < 512) ? wih1[col * 512 + k] : whh1[col * 512 + (k - 512)];
    wl1[j] = f2b(v);
  } else if (i < NA + NB + N1 + N2) {
    int j = i - NA - NB - N1, col = j >> 9, k = j & 511;
    wlin[j] = f2b(wlinf[col * 512 + k]);
  }
}

// 136 persistent WGs, XCD-local tiles (tile = bid&7, slot w = bid>>3),
// runtime-verified via XCC_ID handshake (agent fallback if not co-XCD).
// Per-chain protocol = round-9 champion: tick tau consumes h0(tau-1)
// [slot (tau-1)&1] and h1(tau-2) [slot tau&1]; produces h0(tau) [slot
// tau&1], h1(tau-1) [slot (tau+1)&1]. Gate: chain's 17 flag words >=
// tau+1. WAR audit identical per chain (disjoint row ranges).
__global__ __launch_bounds__(256, 1) void lstm_kernel(
    const float* __restrict__ bih0, const float* __restrict__ bhh0,
    const float* __restrict__ bih1, const float* __restrict__ bhh1,
    const float* __restrict__ blin,
    const int* __restrict__ z, const int* __restrict__ nfr,
    const u16* __restrict__ wl0a, const u16* __restrict__ wl0b,
    const u16* __restrict__ wl1, const u16* __restrict__ wlin,
    u16* __restrict__ h0buf, u16* __restrict__ h1buf,
    u32* __restrict__ bars, float* __restrict__ out) {
  extern __shared__ char smem[];
  u16* AA = (u16*)smem;
  u16* AB = (u16*)(smem + AB_OFF_B);
  float* GfA = (float*)(smem + GA_OFF_B);
  float* GfB = (float*)(smem + GB_OFF_B);
  float* Pm = (float*)(smem + P_OFF_B);
  float* Ps = Pm + 256;
  float* Pt = Ps + 256;
  const int wg = blockIdx.x;
  const int w_all = wg >> 3;            // slot on the XCD: 0..16
  const bool isC = (w_all < 16);
  const int tile = wg & 7;
  const int w = isC ? w_all : 16;
  const int slot = isC ? w : 16;        // flag-word slot
  const int tid = threadIdx.x, lane = tid & 63, wv = tid >> 6;
  const int l15 = lane & 15, l4 = lane >> 4;
  const int row0 = tile * 32;
  const int rowA = row0, rowB = row0 + 16;
  u32* FA = bars + tile * 48;           // A flags: words 0..16
  u32* FB = FA + 20;                    // B flags: words 20..36
  const f32x4 VZ = {0.f, 0.f, 0.f, 0.f};
  // cell mapping (16 rows/chain): thread -> (row rC2, 2 units u0C2..+1)
  const int rC2 = tid >> 4, u0C2 = (tid & 15) * 2;
  // logits mapping (per chain): 16 rows x 16 col-groups of 8
  const int rL = tid & 15, kL = tid >> 4;

  float c0A[2] = {0, 0}, c1A[2] = {0, 0};
  float c0B[2] = {0, 0}, c1B[2] = {0, 0};
  float accNA = 0.f, accNB = 0.f, nflA = 0.f, nflB = 0.f;
  float bias0c[2], bias1c[2], biasLc[2];
  bf16x8 bq0R[32];                  // L0 W_hh0: 2 cb x 16 kb
  bf16x8 bq1R[64];                  // L1: 2 cb x 32 kb
  bf16x8 wlR[32];                   // logits

  if (isC) {
#pragma unroll
    for (int cb = 0; cb < 2; ++cb) {
      int col = wv * 512 + w * 32 + cb * 16 + l15;
      bias0c[cb] = bih0[col] + bhh0[col];
      bias1c[cb] = bih1[col] + bhh1[col];
      const u16* b0 = wl0a + (size_t)col * 512 + l4 * 8;
#pragma unroll
      for (int kb = 0; kb < 16; ++kb) bq0R[cb * 16 + kb] = *(const bf16x8*)(b0 + kb * 32);
      const u16* b1 = wl1 + (size_t)col * 1024 + l4 * 8;
#pragma unroll
      for (int kb = 0; kb < 32; ++kb) bq1R[cb * 32 + kb] = *(const bf16x8*)(b1 + kb * 32);
    }
  } else {
#pragma unroll
    for (int cb = 0; cb < 2; ++cb) {
      int colV = wv * 32 + cb * 16 + l15;
      biasLc[cb] = blin[colV];
      const u16* bL = wlin + (size_t)colV * 512 + l4 * 8;
#pragma unroll
      for (int kb = 0; kb < 16; ++kb) wlR[cb * 16 + kb] = *(const bf16x8*)(bL + kb * 32);
    }
    if (kL == 0) { nflA = (float)nfr[rowA + rL]; nflB = (float)nfr[rowB + rL]; }
  }

  // ---- one-time XCD co-residency handshake (agent scope) ----
  // bars u32 layout: per-tile 48-word block (flags); [384..391] tile XCD
  // masks; [392] grid init counter. All inside the 2KB memset.
  u32 xcc;
  asm volatile("s_getreg_b32 %0, hwreg(HW_REG_XCC_ID)" : "=s"(xcc));
  {
    int* hls = (int*)Pm;
    if (tid == 0) {
      u32 bit = 1u << (xcc & 31u);
      __hip_atomic_fetch_or(bars + 384 + tile, bit, __ATOMIC_RELAXED, __HIP_MEMORY_SCOPE_AGENT);
      __hip_atomic_fetch_add(bars + 392, 1u, __ATOMIC_RELAXED, __HIP_MEMORY_SCOPE_AGENT);
      while (__hip_atomic_load(bars + 392, __ATOMIC_RELAXED, __HIP_MEMORY_SCOPE_AGENT) < (u32)NWG)
        __builtin_amdgcn_s_sleep(1);
      u32 m = __hip_atomic_load(bars + 384 + tile, __ATOMIC_RELAXED, __HIP_MEMORY_SCOPE_AGENT);
      hls[0] = (m == bit) ? 1 : 0;
    }
    __syncthreads();
    const_cast<volatile int&>(hls[0]);
  }
  const bool lok = (((volatile int*)Pm)[0] != 0);
  __syncthreads();

  if (isC && w == 0) {
    u64* z0 = (u64*)(h0buf + HB + row0 * 512);
    u64* z1 = (u64*)(h1buf + row0 * 512);
    u64* z2 = (u64*)(h1buf + HB + row0 * 512);
    if (lok) {
      for (int k = tid; k < 2048; k += 256) { z0[k] = 0; z1[k] = 0; z2[k] = 0; }
    } else {
      for (int k = tid; k < 2048; k += 256) { st_coh8(z0 + k, 0); st_coh8(z1 + k, 0); st_coh8(z2 + k, 0); }
    }
  }
  __syncthreads();   // full drain: init stores visible before flag init
  if (tid == 0) {
    if (lok) { fpost_l(FA + slot, 1u); fpost_l(FB + slot, 1u); }
    else     { fpost_a(FA + slot, 1u); fpost_a(FB + slot, 1u); }
  }

  auto ldAA = [&](int kb) {
    return *(const bf16x8*)(AA + l15 * A_ST + kb * 32 + l4 * 8);
  };
  auto ldAB = [&](int kb) {
    return *(const bf16x8*)(AB + l15 * A_ST + kb * 32 + l4 * 8);
  };

#pragma unroll 1
  for (int tau = 0; tau <= TT + 1; ++tau) {
    const bool l0act = isC && (tau < TT);
    const bool l1act = isC && (tau >= 1 && tau <= TT);
    const bool lgact = (tau >= 2);

    // ===================== CHAIN A (rows rowA..rowA+15) =====================
    if (wv == 0) wave_poll(FA, lane, (u32)(tau + 1), lok);
    __syncthreads();  // B1
    if (lok) l1inv();
    {
      const u16* h0src = h0buf + ((tau + 1) & 1) * HB + rowA * 512;
      const u64* h1s = (const u64*)(h1buf + (tau & 1) * HB + rowA * 512);
      if (isC) {
        if (tau <= TT) {
          u64 ta[4], tb[4];
          const u64* s64 = (const u64*)h0src;
          if (lok) {
#pragma unroll
            for (int c = 0; c < 4; ++c) { int li = c * 256 + tid; ta[c] = s64[li * 2]; tb[c] = s64[li * 2 + 1]; }
          } else {
#pragma unroll
            for (int c = 0; c < 4; ++c) { int li = c * 256 + tid; ta[c] = ld_coh8(s64 + li * 2); tb[c] = ld_coh8(s64 + li * 2 + 1); }
          }
#pragma unroll
          for (int c = 0; c < 4; ++c) {
            int li = c * 256 + tid, row = li >> 6, cc = li & 63;
            u64* d = (u64*)(AA + row * A_ST + cc * 8);
            d[0] = ta[c]; d[1] = tb[c];
          }
        }
        u64 ha[2], hb[2];
        if (l1act) {
          if (lok) {
#pragma unroll
            for (int c = 0; c < 2; ++c) { int li = c * 256 + tid; ha[c] = h1s[li * 2]; hb[c] = h1s[li * 2 + 1]; }
          } else {
#pragma unroll
            for (int c = 0; c < 2; ++c) { int li = c * 256 + tid; ha[c] = ld_coh8(h1s + li * 2); hb[c] = ld_coh8(h1s + li * 2 + 1); }
          }
        }
        __syncthreads();  // B2

        f32x4 acc0[2] = {VZ, VZ}, acc1[2] = {VZ, VZ};
        if (l0act) {
#pragma unroll
          for (int kb = 0; kb < 16; ++kb) {
            bf16x8 a0 = ldAA(kb);
#pragma unroll
            for (int cb = 0; cb < 2; ++cb)
              acc0[cb] = __builtin_amdgcn_mfma_f32_16x16x32_bf16(a0, bq0R[cb * 16 + kb], acc0[cb], 0, 0, 0);
          }
        }
        if (l1act) {
#pragma unroll
          for (int kb = 0; kb < 16; ++kb) {
            bf16x8 a0 = ldAA(kb);
#pragma unroll
            for (int cb = 0; cb < 2; ++cb)
              acc1[cb] = __builtin_amdgcn_mfma_f32_16x16x32_bf16(a0, bq1R[cb * 32 + kb], acc1[cb], 0, 0, 0);
          }
        }
        if (l0act) {
#pragma unroll
          for (int cb = 0; cb < 2; ++cb)
#pragma unroll
            for (int q = 0; q < 4; ++q)
              GfA[(l4 * 4 + q) * 129 + wv * 32 + cb * 16 + l15] = acc0[cb][q] + bias0c[cb];
        }
        __syncthreads();  // B3

        u64 ha2[2], hb2[2];
        if (l1act) {
          if (lok) {
#pragma unroll
            for (int c = 0; c < 2; ++c) { int li = (c + 2) * 256 + tid; ha2[c] = h1s[li * 2]; hb2[c] = h1s[li * 2 + 1]; }
          } else {
#pragma unroll
            for (int c = 0; c < 2; ++c) { int li = (c + 2) * 256 + tid; ha2[c] = ld_coh8(h1s + li * 2); hb2[c] = ld_coh8(h1s + li * 2 + 1); }
          }
        }
        if (l0act) {
          float g4[4][2];
#pragma unroll
          for (int g = 0; g < 4; ++g)
#pragma unroll
            for (int j = 0; j < 2; ++j) g4[g][j] = GfA[rC2 * 129 + g * 32 + u0C2 + j];
          if (tau >= 1) {
            int zr = z[(rowA + rC2) * TT + (tau - 1)];
            const u16* gb = wl0b + (size_t)zr * 2048 + w * 32 + u0C2;
#pragma unroll
            for (int g = 0; g < 4; ++g) {
              u32 v = *(const u32*)(gb + g * 512);
              g4[g][0] += b2f((u16)v); g4[g][1] += b2f((u16)(v >> 16));
            }
          }
          u32 pk = 0;
#pragma unroll
          for (int j = 0; j < 2; ++j) {
            float cn = sigf(g4[1][j]) * c0A[j] + sigf(g4[0][j]) * tanh_f(g4[2][j]);
            float hn = sigf(g4[3][j]) * tanh_f(cn);
            c0A[j] = cn;
            pk |= ((u32)f2b(hn)) << (16 * j);
          }
          u16* h0w = h0buf + (tau & 1) * HB + rowA * 512;
          u32* dst = (u32*)(h0w + rC2 * 512 + w * 32 + u0C2);
          if (lok) *dst = pk; else st_coh4(dst, pk);
        }
        if (l1act) {
#pragma unroll
          for (int c = 0; c < 2; ++c) {
            int li = c * 256 + tid, row = li >> 6, cc = li & 63;
            u64* d = (u64*)(AA + row * A_ST + cc * 8);
            d[0] = ha[c]; d[1] = hb[c];
          }
#pragma unroll
          for (int c = 0; c < 2; ++c) {
            int li = (c + 2) * 256 + tid, row = li >> 6, cc = li & 63;
            u64* d = (u64*)(AA + row * A_ST + cc * 8);
            d[0] = ha2[c]; d[1] = hb2[c];
          }
        }
        __syncthreads();  // B4

        if (l1act) {
#pragma unroll
          for (int kb = 16; kb < 32; ++kb) {
            bf16x8 a0 = ldAA(kb - 16);
#pragma unroll
            for (int cb = 0; cb < 2; ++cb)
              acc1[cb] = __builtin_amdgcn_mfma_f32_16x16x32_bf16(a0, bq1R[cb * 32 + kb], acc1[cb], 0, 0, 0);
          }
#pragma unroll
          for (int cb = 0; cb < 2; ++cb)
#pragma unroll
            for (int q = 0; q < 4; ++q)
              GfA[(l4 * 4 + q) * 129 + wv * 32 + cb * 16 + l15] = acc1[cb][q] + bias1c[cb];
        }
        __syncthreads();  // B5

        if (l1act) {
          float g4[4][2];
#pragma unroll
          for (int g = 0; g < 4; ++g)
#pragma unroll
            for (int j = 0; j < 2; ++j) g4[g][j] = GfA[rC2 * 129 + g * 32 + u0C2 + j];
          u32 pk = 0;
#pragma unroll
          for (int j = 0; j < 2; ++j) {
            float cn = sigf(g4[1][j]) * c1A[j] + sigf(g4[0][j]) * tanh_f(g4[2][j]);
            float hn = sigf(g4[3][j]) * tanh_f(cn);
            c1A[j] = cn;
            pk |= ((u32)f2b(hn)) << (16 * j);
          }
          u16* h1w = h1buf + ((tau + 1) & 1) * HB + rowA * 512;
          u32* dst = (u32*)(h1w + rC2 * 512 + w * 32 + u0C2);
          if (lok) *dst = pk; else st_coh4(dst, pk);
        }
        __syncthreads();  // B6: drain => stores visible before flag
        if (tid == 0) { if (lok) fpost_l(FA + slot, (u32)(tau + 2)); else fpost_a(FA + slot, (u32)(tau + 2)); }
      } else {
        // -------- logits, chain A --------
        if (lgact) {
          u64 ta[4], tb[4];
          if (lok) {
#pragma unroll
            for (int c = 0; c < 4; ++c) { int li = c * 256 + tid; ta[c] = h1s[li * 2]; tb[c] = h1s[li * 2 + 1]; }
          } else {
#pragma unroll
            for (int c = 0; c < 4; ++c) { int li = c * 256 + tid; ta[c] = ld_coh8(h1s + li * 2); tb[c] = ld_coh8(h1s + li * 2 + 1); }
          }
#pragma unroll
          for (int c = 0; c < 4; ++c) {
            int li = c * 256 + tid, row = li >> 6, cc = li & 63;
            u64* d = (u64*)(AA + row * A_ST + cc * 8);
            d[0] = ta[c]; d[1] = tb[c];
          }
        }
        __syncthreads();  // B2: staged
        if (tid == 0) { if (lok) fpost_l(FA + slot, (u32)(tau + 2)); else fpost_a(FA + slot, (u32)(tau + 2)); }
        if (lgact) {
          f32x4 accL[2] = {VZ, VZ};
#pragma unroll
          for (int kb = 0; kb < 16; ++kb) {
            bf16x8 a0 = ldAA(kb);
#pragma unroll
            for (int cb = 0; cb < 2; ++cb)
              accL[cb] = __builtin_amdgcn_mfma_f32_16x16x32_bf16(a0, wlR[cb * 16 + kb], accL[cb], 0, 0, 0);
          }
#pragma unroll
          for (int cb = 0; cb < 2; ++cb)
#pragma unroll
            for (int q = 0; q < 4; ++q)
              GfA[(l4 * 4 + q) * 129 + wv * 32 + cb * 16 + l15] = accL[cb][q] + biasLc[cb];
        }
        __syncthreads();  // B3
        if (lgact) {
          int t2 = tau - 2;
          float vloc[8], mloc = -3.4e38f;
#pragma unroll
          for (int j = 0; j < 8; ++j) {
            vloc[j] = GfA[rL * 129 + kL * 8 + j];
            mloc = fmaxf(mloc, vloc[j]);
          }
          Pm[rL * 16 + kL] = mloc;
          __syncthreads();
          float mrow = Pm[rL * 16];
#pragma unroll
          for (int j = 1; j < 16; ++j) mrow = fmaxf(mrow, Pm[rL * 16 + j]);
          int zr = z[(rowA + rL) * TT + t2];
          float sloc = 0.f, tloc = 0.f;
#pragma unroll
          for (int j = 0; j < 8; ++j) {
            sloc += __expf(vloc[j] - mrow);
            tloc += (kL * 8 + j == zr) ? vloc[j] : 0.f;
          }
          Ps[rL * 16 + kL] = sloc; Pt[rL * 16 + kL] = tloc;
          __syncthreads();
          if (kL == 0) {
            float s = 0.f, tv = 0.f;
#pragma unroll
            for (int j = 0; j < 16; ++j) { s += Ps[rL * 16 + j]; tv += Pt[rL * 16 + j]; }
            if ((float)t2 < nflA) accNA += mrow + __logf(s) - tv;
          }
        } else {
          __syncthreads(); __syncthreads();
        }
      }
    }

    // ===================== CHAIN B (rows rowB..rowB+15) =====================
    if (wv == 0) wave_poll(FB, lane, (u32)(tau + 1), lok);
    __syncthreads();  // B1
    if (lok) l1inv();
    {
      const u16* h0src = h0buf + ((tau + 1) & 1) * HB + rowB * 512;
      const u64* h1s = (const u64*)(h1buf + (tau & 1) * HB + rowB * 512);
      if (isC) {
        if (tau <= TT) {
          u64 ta[4], tb[4];
          const u64* s64 = (const u64*)h0src;
          if (lok) {
#pragma unroll
            for (int c = 0; c < 4; ++c) { int li = c * 256 + tid; ta[c] = s64[li * 2]; tb[c] = s64[li * 2 + 1]; }
          } else {
#pragma unroll
            for (int c = 0; c < 4; ++c) { int li = c * 256 + tid; ta[c] = ld_coh8(s64 + li * 2); tb[c] = ld_coh8(s64 + li * 2 + 1); }
          }
#pragma unroll
          for (int c = 0; c < 4; ++c) {
            int li = c * 256 + tid, row = li >> 6, cc = li & 63;
            u64* d = (u64*)(AB + row * A_ST + cc * 8);
            d[0] = ta[c]; d[1] = tb[c];
          }
        }
        u64 ha[2], hb[2];
        if (l1act) {
          if (lok) {
#pragma unroll
            for (int c = 0; c < 2; ++c) { int li = c * 256 + tid; ha[c] = h1s[li * 2]; hb[c] = h1s[li * 2 + 1]; }
          } else {
#pragma unroll
            for (int c = 0; c < 2; ++c) { int li = c * 256 + tid; ha[c] = ld_coh8(h1s + li * 2); hb[c] = ld_coh8(h1s + li * 2 + 1); }
          }
        }
        __syncthreads();  // B2

        f32x4 acc0[2] = {VZ, VZ}, acc1[2] = {VZ, VZ};
        if (l0act) {
#pragma unroll
          for (int kb = 0; kb < 16; ++kb) {
            bf16x8 a0 = ldAB(kb);
#pragma unroll
            for (int cb = 0; cb < 2; ++cb)
              acc0[cb] = __builtin_amdgcn_mfma_f32_16x16x32_bf16(a0, bq0R[cb * 16 + kb], acc0[cb], 0, 0, 0);
          }
        }
        if (l1act) {
#pragma unroll
          for (int kb = 0; kb < 16; ++kb) {
            bf16x8 a0 = ldAB(kb);
#pragma unroll
            for (int cb = 0; cb < 2; ++cb)
              acc1[cb] = __builtin_amdgcn_mfma_f32_16x16x32_bf16(a0, bq1R[cb * 32 + kb], acc1[cb], 0, 0, 0);
          }
        }
        if (l0act) {
#pragma unroll
          for (int cb = 0; cb < 2; ++cb)
#pragma unroll
            for (int q = 0; q < 4; ++q)
              GfB[(l4 * 4 + q) * 129 + wv * 32 + cb * 16 + l15] = acc0[cb][q] + bias0c[cb];
        }
        __syncthreads();  // B3

        u64 ha2[2], hb2[2];
        if (l1act) {
          if (lok) {
#pragma unroll
            for (int c = 0; c < 2; ++c) { int li = (c + 2) * 256 + tid; ha2[c] = h1s[li * 2]; hb2[c] = h1s[li * 2 + 1]; }
          } else {
#pragma unroll
            for (int c = 0; c < 2; ++c) { int li = (c + 2) * 256 + tid; ha2[c] = ld_coh8(h1s + li * 2); hb2[c] = ld_coh8(h1s + li * 2 + 1); }
          }
        }
        if (l0act) {
          float g4[4][2];
#pragma unroll
          for (int g = 0; g < 4; ++g)
#pragma unroll
            for (int j = 0; j < 2; ++j) g4[g][j] = GfB[rC2 * 129 + g * 32 + u0C2 + j];
          if (tau >= 1) {
            int zr = z[(rowB + rC2) * TT + (tau - 1)];
            const u16* gb = wl0b + (size_t)zr * 2048 + w * 32 + u0C2;
#pragma unroll
            for (int g = 0; g < 4; ++g) {
              u32 v = *(const u32*)(gb + g * 512);
              g4[g][0] += b2f((u16)v); g4[g][1] += b2f((u16)(v >> 16));
            }
          }
          u32 pk = 0;
#pragma unroll
          for (int j = 0; j < 2; ++j) {
            float cn = sigf(g4[1][j]) * c0B[j] + sigf(g4[0][j]) * tanh_f(g4[2][j]);
            float hn = sigf(g4[3][j]) * tanh_f(cn);
            c0B[j] = cn;
            pk |= ((u32)f2b(hn)) << (16 * j);
          }
          u16* h0w = h0buf + (tau & 1) * HB + rowB * 512;
          u32* dst = (u32*)(h0w + rC2 * 512 + w * 32 + u0C2);
          if (lok) *dst = pk; else st_coh4(dst, pk);
        }
        if (l1act) {
#pragma unroll
          for (int c = 0; c < 2; ++c) {
            int li = c * 256 + tid, row = li >> 6, cc = li & 63;
            u64* d = (u64*)(AB + row * A_ST + cc * 8);
            d[0] = ha[c]; d[1] = hb[c];
          }
#pragma unroll
          for (int c = 0; c < 2; ++c) {
            int li = (c + 2) * 256 + tid, row = li >> 6, cc = li & 63;
            u64* d = (u64*)(AB + row * A_ST + cc * 8);
            d[0] = ha2[c]; d[1] = hb2[c];
          }
        }
        __syncthreads();  // B4

        if (l1act) {
#pragma unroll
          for (int kb = 16; kb < 32; ++kb) {
            bf16x8 a0 = ldAB(kb - 16);
#pragma unroll
            for (int cb = 0; cb < 2; ++cb)
              acc1[cb] = __builtin_amdgcn_mfma_f32_16x16x32_bf16(a0, bq1R[cb * 32 + kb], acc1[cb], 0, 0, 0);
          }
#pragma unroll
          for (int cb = 0; cb < 2; ++cb)
#pragma unroll
            for (int q = 0; q < 4; ++q)
              GfB[(l4 * 4 + q) * 129 + wv * 32 + cb * 16 + l15] = acc1[cb][q] + bias1c[cb];
        }
        __syncthreads();  // B5

        if (l1act) {
          float g4[4][2];
#pragma unroll
          for (int g = 0; g < 4; ++g)
#pragma unroll
            for (int j = 0; j < 2; ++j) g4[g][j] = GfB[rC2 * 129 + g * 32 + u0C2 + j];
          u32 pk = 0;
#pragma unroll
          for (int j = 0; j < 2; ++j) {
            float cn = sigf(g4[1][j]) * c1B[j] + sigf(g4[0][j]) * tanh_f(g4[2][j]);
            float hn = sigf(g4[3][j]) * tanh_f(cn);
            c1B[j] = cn;
            pk |= ((u32)f2b(hn)) << (16 * j);
          }
          u16* h1w = h1buf + ((tau + 1) & 1) * HB + rowB * 512;
          u32* dst = (u32*)(h1w + rC2 * 512 + w * 32 + u0C2);
          if (lok) *dst = pk; else st_coh4(dst, pk);
        }
        __syncthreads();  // B6
        if (tid == 0) { if (lok) fpost_l(FB + slot, (u32)(tau + 2)); else fpost_a(FB + slot, (u32)(tau + 2)); }
      } else {
        // -------- logits, chain B --------
        if (lgact) {
          u64 ta[4], tb[4];
          if (lok) {
#pragma unroll
            for (int c = 0; c < 4; ++c) { int li = c * 256 + tid; ta[c] = h1s[li * 2]; tb[c] = h1s[li * 2 + 1]; }
          } else {
#pragma unroll
            for (int c = 0; c < 4; ++c) { int li = c * 256 + tid; ta[c] = ld_coh8(h1s + li * 2); tb[c] = ld_coh8(h1s + li * 2 + 1); }
          }
#pragma unroll
          for (int c = 0; c < 4; ++c) {
            int li = c * 256 + tid, row = li >> 6, cc = li & 63;
            u64* d = (u64*)(AB + row * A_ST + cc * 8);
            d[0] = ta[c]; d[1] = tb[c];
          }
        }
        __syncthreads();  // B2: staged
        if (tid == 0) { if (lok) fpost_l(FB + slot, (u32)(tau + 2)); else fpost_a(FB + slot, (u32)(tau + 2)); }
        if (lgact) {
          f32x4 accL[2] = {VZ, VZ};
#pragma unroll
          for (int kb = 0; kb < 16; ++kb) {
            bf16x8 a0 = ldAB(kb);
#pragma unroll
            for (int cb = 0; cb < 2; ++cb)
              accL[cb] = __builtin_amdgcn_mfma_f32_16x16x32_bf16(a0, wlR[cb * 16 + kb], accL[cb], 0, 0, 0);
          }
#pragma unroll
          for (int cb = 0; cb < 2; ++cb)
#pragma unroll
            for (int q = 0; q < 4; ++q)
              GfB[(l4 * 4 + q) * 129 + wv * 32 + cb * 16 + l15] = accL[cb][q] + biasLc[cb];
        }
        __syncthreads();  // B3
        if (lgact) {
          int t2 = tau - 2;
          float vloc[8], mloc = -3.4e38f;
#pragma unroll
          for (int j = 0; j < 8; ++j) {
            vloc[j] = GfB[rL * 129 + kL * 8 + j];
            mloc = fmaxf(mloc, vloc[j]);
          }
          Pm[rL * 16 + kL] = mloc;
          __syncthreads();
          float mrow = Pm[rL * 16];
#pragma unroll
          for (int j = 1; j < 16; ++j) mrow = fmaxf(mrow, Pm[rL * 16 + j]);
          int zr = z[(rowB + rL) * TT + t2];
          float sloc = 0.f, tloc = 0.f;
#pragma unroll
          for (int j = 0; j < 8; ++j) {
            sloc += __expf(vloc[j] - mrow);
            tloc += (kL * 8 + j == zr) ? vloc[j] : 0.f;
          }
          Ps[rL * 16 + kL] = sloc; Pt[rL * 16 + kL] = tloc;
          __syncthreads();
          if (kL == 0) {
            float s = 0.f, tv = 0.f;
#pragma unroll
            for (int j = 0; j < 16; ++j) { s += Ps[rL * 16 + j]; tv += Pt[rL * 16 + j]; }
            if ((float)t2 < nflB) accNB += mrow + __logf(s) - tv;
          }
        } else {
          __syncthreads(); __syncthreads();
        }
      }
    }
  }

  if (!isC && kL == 0) {
    out[rowA + rL] = accNA * (1.0f / TT);
    out[rowB + rL] = accNB * (1.0f / TT);
  }
}

extern "C" void kernel_launch(void* const* d_in, const int* in_sizes, int n_in,
                              void* d_out, int out_size, void* d_ws, size_t ws_size,
                              hipStream_t stream) {
  const float* wih0 = (const float*)d_in[0];
  const float* whh0 = (const float*)d_in[1];
  const float* bih0 = (const float*)d_in[2];
  const float* bhh0 = (const float*)d_in[3];
  const float* wih1 = (const float*)d_in[4];
  const float* whh1 = (const float*)d_in[5];
  const float* bih1 = (const float*)d_in[6];
  const float* bhh1 = (const float*)d_in[7];
  const float* wlinf = (const float*)d_in[8];
  const float* blin = (const float*)d_in[9];
  const int* z = (const int*)d_in[10];
  const int* nfr = (const int*)d_in[11];
  float* out = (float*)d_out;
  char* ws = (char*)d_ws;
  u16* wl0a = (u16*)(ws + WL0A_OFF);
  u16* wl0b = (u16*)(ws + WL0B_OFF);
  u16* wl1 = (u16*)(ws + WL1_OFF);
  u16* wlin = (u16*)(ws + WLIN_OFF);
  u16* h0buf = (u16*)(ws + H0_OFF);
  u16* h1buf = (u16*)(ws + H1_OFF);
  u32* bars = (u32*)(ws + BAR_OFF);

  hipMemsetAsync(ws + BAR_OFF, 0, 2048, stream);
  const int NTOT = 2048 * 512 + 128 * 2048 + 2048 * 1024 + 128 * 512;
  prep_kernel<<<dim3((NTOT + 255) / 256), dim3(256), 0, stream>>>(
      wih0, whh0, wih1, whh1, wlinf, wl0a, wl0b, wl1, wlin);
  lstm_kernel<<<dim3(NWG), dim3(256), LDS_BYTES, stream>>>(
      bih0, bhh0, bih1, bhh1, blin, z, nfr, wl0a, wl0b, wl1, wlin, h0buf, h1buf, bars, out);
}

// Round 13
// 7584.133 us; speedup vs baseline: 1.5856x; 1.5856x over previous
//
#include <hip/hip_runtime.h>

#define TT 800

typedef __attribute__((ext_vector_type(8))) short bf16x8;
typedef __attribute__((ext_vector_type(4))) float f32x4;
typedef __attribute__((ext_vector_type(2))) unsigned long long u64x2;
typedef unsigned short u16;
typedef unsigned int u32;
typedef unsigned long long u64;

constexpr int NCW = 128, NWG = 136, RT = 32;
constexpr size_t WL0A_OFF = 0;              // [2048][512] bf16 = 2,097,152 (W_hh0, K-major)
constexpr size_t WL0B_OFF = 2097152;        // [128][2048] bf16 = 524,288  (W_ih0^T row-gather)
constexpr size_t WL1_OFF  = 2621440;        // [2048][1024] bf16
constexpr size_t WLIN_OFF = 6815744;        // [128][512] bf16
constexpr size_t H0_OFF   = 6946816;        // [2][256][512] bf16
constexpr size_t H1_OFF   = 7471104;        // [2][256][512] bf16
constexpr size_t BAR_OFF  = 7995392;        // flag words(1KB) + handshake (within 2KB memset)
constexpr int HB = 256 * 512;
// LDS: A = 32 rows x 520 u16 = 33280 B; Gf = 32 x 129 f32 = 16512 B @33280;
// P = 3 x 256 f32 = 3072 B @49792. Total 52864 (<64K, no opt-in needed).
constexpr int A_ST = 520;
constexpr int G_OFF_B = 33280;
constexpr int P_OFF_B = 49792;
constexpr int LDS_BYTES = 53248;

__device__ __forceinline__ u16 f2b(float x) {
  u32 u = __float_as_uint(x);
  return (u16)((u + 0x7FFFu + ((u >> 16) & 1u)) >> 16);   // RNE fp32->bf16
}
__device__ __forceinline__ float b2f(u16 v) { return __uint_as_float(((u32)v) << 16); }
__device__ __forceinline__ float sigf(float x) { return 1.f / (1.f + __expf(-x)); }
__device__ __forceinline__ float tanh_f(float x) { float e = __expf(2.f * x); return 1.f - 2.f / (e + 1.f); }

// ---- agent-scope (cross-XCD safe) data ops: fallback path ----
__device__ __forceinline__ u64 ld_coh8(const u64* p) {
  return __hip_atomic_load(p, __ATOMIC_RELAXED, __HIP_MEMORY_SCOPE_AGENT);
}
__device__ __forceinline__ void st_coh8(u64* p, u64 v) {
  __hip_atomic_store(p, v, __ATOMIC_RELAXED, __HIP_MEMORY_SCOPE_AGENT);
}
// ---- Flag transport (round-9, champion): per-WG flag WORDS, no RMW.
// WG s stores (tau+2) into its own word bars[tile*32+s] (plain posted
// store in lok — h stores are DRAINED by B6's vmcnt0 before the flag
// store issues, so visibility order is safe). Waiter: lanes 0..16 of
// wave 0 load all 17 words in one coalesced read and spin on __all.
// lok retry uses buffer_inv (fresh L1); fallback uses agent loads+sleep.
__device__ __forceinline__ void fpost_l(u32* fw, u32 v) {
  *(volatile u32*)fw = v;
}
__device__ __forceinline__ void fpost_a(u32* fw, u32 v) {
  __hip_atomic_store(fw, v, __ATOMIC_RELAXED, __HIP_MEMORY_SCOPE_AGENT);
}
__device__ __forceinline__ void wave_poll(u32* Fw, int lane, u32 thr, bool lok) {
  int idx = (lane < 17) ? lane : 16;
  if (lok) {
    while (true) {
      u32 v = *(volatile u32*)(Fw + idx);
      if (__all((int)(v >= thr))) break;
      asm volatile("buffer_inv" ::: "memory");   // progress vs stale L1 line
    }
  } else {
    while (true) {
      u32 v = __hip_atomic_load(Fw + idx, __ATOMIC_RELAXED, __HIP_MEMORY_SCOPE_AGENT);
      if (__all((int)(v >= thr))) break;
      __builtin_amdgcn_s_sleep(1);
    }
  }
}
__device__ __forceinline__ void l1inv() { asm volatile("buffer_inv" ::: "memory"); }

__global__ void prep_kernel(const float* __restrict__ wih0, const float* __restrict__ whh0,
                            const float* __restrict__ wih1, const float* __restrict__ whh1,
                            const float* __restrict__ wlinf,
                            u16* __restrict__ wl0a, u16* __restrict__ wl0b,
                            u16* __restrict__ wl1, u16* __restrict__ wlin) {
  int i = blockIdx.x * 256 + threadIdx.x;
  const int NA = 2048 * 512, NB = 128 * 2048, N1 = 2048 * 1024, N2 = 128 * 512;
  if (i < NA) {
    int col = i >> 9, k = i & 511;
    wl0a[i] = f2b(whh0[col * 512 + k]);
  } else if (i < NA + NB) {
    int j = i - NA, k = j >> 11, col = j & 2047;
    wl0b[j] = f2b(wih0[col * 128 + k]);
  } else if (i < NA + NB + N1) {
    int j = i - NA - NB, col = j >> 10, k = j & 1023;
    float v = (k < 512) ? wih1[col * 512 + k] : whh1[col * 512 + (k - 512)];
    wl1[j] = f2b(v);
  } else if (i < NA + NB + N1 + N2) {
    int j = i - NA - NB - N1, col = j >> 9, k = j & 511;
    wlin[j] = f2b(wlinf[col * 512 + k]);
  }
}

// 136 persistent WGs, XCD-local tiles (tile = bid&7, slot w = bid>>3),
// runtime-verified via XCC_ID handshake (agent fallback if not co-XCD).
// STRUCTURE = ROUND-9 CHAMPION (7559us): round-2 phases B1..B6 + per-WG
// flag words. Reverted experiments and their measured costs: swap-stores
// (r4 +206, RMW fetches the line), split-flag (r5 +483, extra sync
// events), scoped barriers (r6 +90), merged phases (r7 +1915, spill),
// gather hoist (r8 +1232, spill — NOTHING may be held live across the
// MFMA phase), all-wave poll + dbuf (r10 +1845, multi-wave inv thrash),
// agent h-loads (r11 +668, lost L1 pair-coalescing), dual-chain
// interleave (r12 +4466, doubled sync events / halved amortization).
// Protocol: tick tau consumes h0(tau-1) [slot (tau-1)&1] and h1(tau-2)
// [slot tau&1]; produces h0(tau) [slot tau&1], h1(tau-1) [slot
// (tau+1)&1]. Gate: all 17 flag words >= tau+1.
// ROUND-13 DELTA (local, spill-safe): lok staging loads fused 2x8B ->
// 1x16B (global_load_dwordx4) and LDS writes -> ds_write_b128. Same
// bytes, same lines, same live-register count (8 x u64x2 = ta[8]+tb[8]);
// half the VMEM instructions in the staging phase.
__global__ __launch_bounds__(256, 1) void lstm_kernel(
    const float* __restrict__ bih0, const float* __restrict__ bhh0,
    const float* __restrict__ bih1, const float* __restrict__ bhh1,
    const float* __restrict__ blin,
    const int* __restrict__ z, const int* __restrict__ nfr,
    const u16* __restrict__ wl0a, const u16* __restrict__ wl0b,
    const u16* __restrict__ wl1, const u16* __restrict__ wlin,
    u16* __restrict__ h0buf, u16* __restrict__ h1buf,
    u32* __restrict__ bars, float* __restrict__ out) {
  extern __shared__ char smem[];
  u16* A = (u16*)smem;
  float* Gf = (float*)(smem + G_OFF_B);
  float* Pm = (float*)(smem + P_OFF_B);
  float* Ps = Pm + 256;
  float* Pt = Ps + 256;
  const int wg = blockIdx.x;
  const int w_all = wg >> 3;            // slot on the XCD: 0..16
  const bool isC = (w_all < 16);
  const int tile = wg & 7;              // XCD id; all 17 WGs of a tile co-XCD
  const int w = isC ? w_all : 16;
  const int slot = isC ? w : 16;        // flag-word slot
  const int tid = threadIdx.x, lane = tid & 63, wv = tid >> 6;
  const int l15 = lane & 15, l4 = lane >> 4;
  const int row0 = tile * RT;
  u32* Fw = bars + tile * 32;           // 17 words in one 128B line
  const f32x4 VZ = {0.f, 0.f, 0.f, 0.f};
  // cell-phase mapping: thread -> (row rC, 4 consecutive units u0C..+3)
  const int rC = tid >> 3, u0C = (tid & 7) * 4;
  // logits softmax mapping
  const int cuL = tid & 31, rgL = tid >> 5;

  float c0s[4] = {0, 0, 0, 0}, c1s[4] = {0, 0, 0, 0};
  float accN = 0.f, nflv = 0.f;
  float bias0c[2], bias1c[2], biasLc[2];
  bf16x8 bq0R[32];                  // L0 W_hh0: 2 cb x 16 kb = 128 reg
  bf16x8 bq1R[64];                  // L1: 2 cb x 32 kb = 256 reg (AGPR)
  bf16x8 wlR[32];                   // logits: 2 cb x 16 kb (shares slots w/ bq0R path)

  if (isC) {
#pragma unroll
    for (int cb = 0; cb < 2; ++cb) {
      int col = wv * 512 + w * 32 + cb * 16 + l15;   // gate wv, half cb
      bias0c[cb] = bih0[col] + bhh0[col];
      bias1c[cb] = bih1[col] + bhh1[col];
      const u16* b0 = wl0a + (size_t)col * 512 + l4 * 8;
#pragma unroll
      for (int kb = 0; kb < 16; ++kb) bq0R[cb * 16 + kb] = *(const bf16x8*)(b0 + kb * 32);
      const u16* b1 = wl1 + (size_t)col * 1024 + l4 * 8;
#pragma unroll
      for (int kb = 0; kb < 32; ++kb) bq1R[cb * 32 + kb] = *(const bf16x8*)(b1 + kb * 32);
    }
  } else {
#pragma unroll
    for (int cb = 0; cb < 2; ++cb) {
      int colV = wv * 32 + cb * 16 + l15;
      biasLc[cb] = blin[colV];
      const u16* bL = wlin + (size_t)colV * 512 + l4 * 8;
#pragma unroll
      for (int kb = 0; kb < 16; ++kb) wlR[cb * 16 + kb] = *(const bf16x8*)(bL + kb * 32);
    }
    if (rgL == 0) nflv = (float)nfr[row0 + cuL];
  }

  // ---- one-time XCD co-residency handshake (agent scope, off hot path) ----
  // bars layout: [0..255] per-tile flag words (tile*32 + slot);
  // [256..263] per-tile XCD masks; [272] grid init counter. All in 2KB memset.
  u32 xcc;
  asm volatile("s_getreg_b32 %0, hwreg(HW_REG_XCC_ID)" : "=s"(xcc));
  {
    int* hls = (int*)Pm;       // LDS broadcast slot (Pm unused until loop)
    if (tid == 0) {
      u32 bit = 1u << (xcc & 31u);
      __hip_atomic_fetch_or(bars + 256 + tile, bit, __ATOMIC_RELAXED, __HIP_MEMORY_SCOPE_AGENT);
      __hip_atomic_fetch_add(bars + 272, 1u, __ATOMIC_RELAXED, __HIP_MEMORY_SCOPE_AGENT);
      while (__hip_atomic_load(bars + 272, __ATOMIC_RELAXED, __HIP_MEMORY_SCOPE_AGENT) < (u32)NWG)
        __builtin_amdgcn_s_sleep(1);
      u32 m = __hip_atomic_load(bars + 256 + tile, __ATOMIC_RELAXED, __HIP_MEMORY_SCOPE_AGENT);
      hls[0] = (m == bit) ? 1 : 0;
    }
    __syncthreads();
    const_cast<volatile int&>(hls[0]);
  }
  const bool lok = (((volatile int*)Pm)[0] != 0);
  __syncthreads();   // everyone has read hls[0]; Pm free for reuse

  if (isC && w == 0) {
    u64* z0 = (u64*)(h0buf + HB + row0 * 512);
    u64* z1 = (u64*)(h1buf + row0 * 512);
    u64* z2 = (u64*)(h1buf + HB + row0 * 512);
    if (lok) {
      for (int k = tid; k < 2048; k += 256) { z0[k] = 0; z1[k] = 0; z2[k] = 0; }
    } else {
      for (int k = tid; k < 2048; k += 256) { st_coh8(z0 + k, 0); st_coh8(z1 + k, 0); st_coh8(z2 + k, 0); }
    }
  }
  __syncthreads();   // full drain: init stores visible before the flag init
  if (tid == 0) { if (lok) fpost_l(Fw + slot, 1u); else fpost_a(Fw + slot, 1u); }

  auto ldA = [&](int rb, int kb) {
    return *(const bf16x8*)(A + (rb * 16 + l15) * A_ST + kb * 32 + l4 * 8);
  };

#pragma unroll 1
  for (int tau = 0; tau <= TT + 1; ++tau) {
    if (wv == 0) wave_poll(Fw, lane, (u32)(tau + 1), lok);
    __syncthreads();  // B1: tick inputs published
    if (lok) l1inv();  // every wave: drop stale h lines from this CU's L1
    const u16* h0src = h0buf + ((tau + 1) & 1) * HB + row0 * 512;
    const u64* h1s64 = (const u64*)(h1buf + (tau & 1) * HB + row0 * 512);
    const bool l0act = isC && (tau < TT);
    const bool l1act = isC && (tau >= 1 && tau <= TT);

    if (isC) {
      // ---- stage h0(tau-1): 8 batched 16B loads -> A (lok) ----
      if (tau <= TT) {
        u64x2 tv[8];
        const u64* s64 = (const u64*)h0src;
        if (lok) {
#pragma unroll
          for (int c = 0; c < 8; ++c) tv[c] = *(const u64x2*)(s64 + (c * 256 + tid) * 2);
        } else {
#pragma unroll
          for (int c = 0; c < 8; ++c) {
            int li = c * 256 + tid;
            tv[c][0] = ld_coh8(s64 + li * 2); tv[c][1] = ld_coh8(s64 + li * 2 + 1);
          }
        }
#pragma unroll
        for (int c = 0; c < 8; ++c) {
          int li = c * 256 + tid, row = li >> 6, cc = li & 63;
          *(u64x2*)(A + row * A_ST + cc * 8) = tv[c];
        }
      }
      // issue h1(tau-2) batch1 (rows 0..15) — in flight across L0+p1 MFMA
      u64x2 hv[4];
      if (l1act) {
        if (lok) {
#pragma unroll
          for (int c = 0; c < 4; ++c) hv[c] = *(const u64x2*)(h1s64 + (c * 256 + tid) * 2);
        } else {
#pragma unroll
          for (int c = 0; c < 4; ++c) {
            int li = c * 256 + tid;
            hv[c][0] = ld_coh8(h1s64 + li * 2); hv[c][1] = ld_coh8(h1s64 + li * 2 + 1);
          }
        }
      }
      __syncthreads();  // B2: A(h0) ready

      f32x4 acc0[2][2] = {{VZ, VZ}, {VZ, VZ}};
      f32x4 acc1[2][2] = {{VZ, VZ}, {VZ, VZ}};
      if (l0act) {
#pragma unroll
        for (int kb = 0; kb < 16; ++kb) {
          bf16x8 a0 = ldA(0, kb), a1 = ldA(1, kb);
#pragma unroll
          for (int cb = 0; cb < 2; ++cb) {
            acc0[0][cb] = __builtin_amdgcn_mfma_f32_16x16x32_bf16(a0, bq0R[cb * 16 + kb], acc0[0][cb], 0, 0, 0);
            acc0[1][cb] = __builtin_amdgcn_mfma_f32_16x16x32_bf16(a1, bq0R[cb * 16 + kb], acc0[1][cb], 0, 0, 0);
          }
        }
      }
      if (l1act) {
        // L1 part 1: K 0..511 (h0(tau-1)) from A, weights in registers
#pragma unroll
        for (int kb = 0; kb < 16; ++kb) {
          bf16x8 a0 = ldA(0, kb), a1 = ldA(1, kb);
#pragma unroll
          for (int cb = 0; cb < 2; ++cb) {
            acc1[0][cb] = __builtin_amdgcn_mfma_f32_16x16x32_bf16(a0, bq1R[cb * 32 + kb], acc1[0][cb], 0, 0, 0);
            acc1[1][cb] = __builtin_amdgcn_mfma_f32_16x16x32_bf16(a1, bq1R[cb * 32 + kb], acc1[1][cb], 0, 0, 0);
          }
        }
      }
      if (l0act) {
#pragma unroll
        for (int rb = 0; rb < 2; ++rb)
#pragma unroll
          for (int cb = 0; cb < 2; ++cb)
#pragma unroll
            for (int q = 0; q < 4; ++q)
              Gf[(rb * 16 + l4 * 4 + q) * 129 + wv * 32 + cb * 16 + l15] = acc0[rb][cb][q] + bias0c[cb];
      }
      __syncthreads();  // B3: Gf(L0) ready AND all A(h0) reads done

      // issue h1 batch2 (rows 16..31) — covered by cell0 VALU
      u64x2 hv2[4];
      if (l1act) {
        if (lok) {
#pragma unroll
          for (int c = 0; c < 4; ++c) hv2[c] = *(const u64x2*)(h1s64 + ((c + 4) * 256 + tid) * 2);
        } else {
#pragma unroll
          for (int c = 0; c < 4; ++c) {
            int li = (c + 4) * 256 + tid;
            hv2[c][0] = ld_coh8(h1s64 + li * 2); hv2[c][1] = ld_coh8(h1s64 + li * 2 + 1);
          }
        }
      }
      if (l0act) {
        // ---- cell0: gates + W_ih0 gather + c/h update, 8B store ----
        float g4[4][4];
#pragma unroll
        for (int g = 0; g < 4; ++g)
#pragma unroll
          for (int j = 0; j < 4; ++j) g4[g][j] = Gf[rC * 129 + g * 32 + u0C + j];
        if (tau >= 1) {
          int zr = z[(row0 + rC) * TT + (tau - 1)];
          const u16* gb = wl0b + (size_t)zr * 2048 + w * 32 + u0C;
#pragma unroll
          for (int g = 0; g < 4; ++g) {
            u64 v = *(const u64*)(gb + g * 512);
#pragma unroll
            for (int j = 0; j < 4; ++j) g4[g][j] += b2f((u16)(v >> (16 * j)));
          }
        }
        u64 pk = 0;
#pragma unroll
        for (int j = 0; j < 4; ++j) {
          float cn = sigf(g4[1][j]) * c0s[j] + sigf(g4[0][j]) * tanh_f(g4[2][j]);
          float hn = sigf(g4[3][j]) * tanh_f(cn);
          c0s[j] = cn;
          pk |= ((u64)f2b(hn)) << (16 * j);
        }
        u16* h0w = h0buf + (tau & 1) * HB + row0 * 512;
        u64* dst = (u64*)(h0w + rC * 512 + w * 32 + u0C);
        if (lok) *dst = pk; else st_coh8(dst, pk);
      }
      if (l1act) {
        // overwrite A with h1(tau-2)
#pragma unroll
        for (int c = 0; c < 4; ++c) {
          int li = c * 256 + tid, row = li >> 6, cc = li & 63;
          *(u64x2*)(A + row * A_ST + cc * 8) = hv[c];
        }
#pragma unroll
        for (int c = 0; c < 4; ++c) {
          int li = (c + 4) * 256 + tid, row = li >> 6, cc = li & 63;
          *(u64x2*)(A + row * A_ST + cc * 8) = hv2[c];
        }
      }
      __syncthreads();  // B4: A(h1) ready AND cell0 Gf reads done

      if (l1act) {
#pragma unroll
        for (int kb = 16; kb < 32; ++kb) {
          bf16x8 a0 = ldA(0, kb - 16), a1 = ldA(1, kb - 16);
#pragma unroll
          for (int cb = 0; cb < 2; ++cb) {
            acc1[0][cb] = __builtin_amdgcn_mfma_f32_16x16x32_bf16(a0, bq1R[cb * 32 + kb], acc1[0][cb], 0, 0, 0);
            acc1[1][cb] = __builtin_amdgcn_mfma_f32_16x16x32_bf16(a1, bq1R[cb * 32 + kb], acc1[1][cb], 0, 0, 0);
          }
        }
#pragma unroll
        for (int rb = 0; rb < 2; ++rb)
#pragma unroll
          for (int cb = 0; cb < 2; ++cb)
#pragma unroll
            for (int q = 0; q < 4; ++q)
              Gf[(rb * 16 + l4 * 4 + q) * 129 + wv * 32 + cb * 16 + l15] = acc1[rb][cb][q] + bias1c[cb];
      }
      __syncthreads();  // B5: Gf(L1) ready

      if (l1act) {
        float g4[4][4];
#pragma unroll
        for (int g = 0; g < 4; ++g)
#pragma unroll
          for (int j = 0; j < 4; ++j) g4[g][j] = Gf[rC * 129 + g * 32 + u0C + j];
        u64 pk = 0;
#pragma unroll
        for (int j = 0; j < 4; ++j) {
          float cn = sigf(g4[1][j]) * c1s[j] + sigf(g4[0][j]) * tanh_f(g4[2][j]);
          float hn = sigf(g4[3][j]) * tanh_f(cn);
          c1s[j] = cn;
          pk |= ((u64)f2b(hn)) << (16 * j);
        }
        u16* h1w = h1buf + ((tau + 1) & 1) * HB + row0 * 512;
        u64* dst = (u64*)(h1w + rC * 512 + w * 32 + u0C);
        if (lok) *dst = pk; else st_coh8(dst, pk);
      }
      __syncthreads();  // B6: per-wave vmcnt(0) drain => stores visible BEFORE flag
      if (tid == 0) { if (lok) fpost_l(Fw + slot, (u32)(tau + 2)); else fpost_a(Fw + slot, (u32)(tau + 2)); }
    } else {
      // ---------------- logits WG: NLL(tau-2) ----------------
      const bool lgact = (tau >= 2);
      if (lgact) {
        u64x2 tv[8];
        if (lok) {
#pragma unroll
          for (int c = 0; c < 8; ++c) tv[c] = *(const u64x2*)(h1s64 + (c * 256 + tid) * 2);
        } else {
#pragma unroll
          for (int c = 0; c < 8; ++c) {
            int li = c * 256 + tid;
            tv[c][0] = ld_coh8(h1s64 + li * 2); tv[c][1] = ld_coh8(h1s64 + li * 2 + 1);
          }
        }
#pragma unroll
        for (int c = 0; c < 8; ++c) {
          int li = c * 256 + tid, row = li >> 6, cc = li & 63;
          *(u64x2*)(A + row * A_ST + cc * 8) = tv[c];
        }
      }
      __syncthreads();  // B2: staged (loads retired)
      if (tid == 0) { if (lok) fpost_l(Fw + slot, (u32)(tau + 2)); else fpost_a(Fw + slot, (u32)(tau + 2)); }  // early release
      if (lgact) {
        f32x4 accL[2][2] = {{VZ, VZ}, {VZ, VZ}};
#pragma unroll
        for (int kb = 0; kb < 16; ++kb) {
          bf16x8 a0 = ldA(0, kb), a1 = ldA(1, kb);
#pragma unroll
          for (int cb = 0; cb < 2; ++cb) {
            accL[0][cb] = __builtin_amdgcn_mfma_f32_16x16x32_bf16(a0, wlR[cb * 16 + kb], accL[0][cb], 0, 0, 0);
            accL[1][cb] = __builtin_amdgcn_mfma_f32_16x16x32_bf16(a1, wlR[cb * 16 + kb], accL[1][cb], 0, 0, 0);
          }
        }
#pragma unroll
        for (int rb = 0; rb < 2; ++rb)
#pragma unroll
          for (int cb = 0; cb < 2; ++cb)
#pragma unroll
            for (int q = 0; q < 4; ++q)
              Gf[(rb * 16 + l4 * 4 + q) * 129 + wv * 32 + cb * 16 + l15] = accL[rb][cb][q] + biasLc[cb];
      }
      __syncthreads();  // B3: Gf ready
      if (lgact) {
        int t2 = tau - 2;
        int r = cuL, k = rgL;            // 8 threads per row x 16 cols
        float vloc[16], mloc = -3.4e38f;
#pragma unroll
        for (int j = 0; j < 16; ++j) {
          vloc[j] = Gf[r * 129 + k * 16 + j];
          mloc = fmaxf(mloc, vloc[j]);
        }
        Pm[r * 8 + k] = mloc;
        __syncthreads();
        float mrow = Pm[r * 8];
#pragma unroll
        for (int j = 1; j < 8; ++j) mrow = fmaxf(mrow, Pm[r * 8 + j]);
        int zr = z[(row0 + r) * TT + t2];
        float sloc = 0.f, tloc = 0.f;
#pragma unroll
        for (int j = 0; j < 16; ++j) {
          sloc += __expf(vloc[j] - mrow);
          tloc += (k * 16 + j == zr) ? vloc[j] : 0.f;
        }
        Ps[r * 8 + k] = sloc; Pt[r * 8 + k] = tloc;
        __syncthreads();
        if (k == 0) {
          float s = 0.f, tv2 = 0.f;
#pragma unroll
          for (int j = 0; j < 8; ++j) { s += Ps[r * 8 + j]; tv2 += Pt[r * 8 + j]; }
          if ((float)t2 < nflv) accN += mrow + __logf(s) - tv2;
        }
      } else {
        __syncthreads(); __syncthreads();
      }
    }
  }

  if (!isC && rgL == 0) out[row0 + cuL] = accN * (1.0f / TT);
}

extern "C" void kernel_launch(void* const* d_in, const int* in_sizes, int n_in,
                              void* d_out, int out_size, void* d_ws, size_t ws_size,
                              hipStream_t stream) {
  const float* wih0 = (const float*)d_in[0];
  const float* whh0 = (const float*)d_in[1];
  const float* bih0 = (const float*)d_in[2];
  const float* bhh0 = (const float*)d_in[3];
  const float* wih1 = (const float*)d_in[4];
  const float* whh1 = (const float*)d_in[5];
  const float* bih1 = (const float*)d_in[6];
  const float* bhh1 = (const float*)d_in[7];
  const float* wlinf = (const float*)d_in[8];
  const float* blin = (const float*)d_in[9];
  const int* z = (const int*)d_in[10];
  const int* nfr = (const int*)d_in[11];
  float* out = (float*)d_out;
  char* ws = (char*)d_ws;
  u16* wl0a = (u16*)(ws + WL0A_OFF);
  u16* wl0b = (u16*)(ws + WL0B_OFF);
  u16* wl1 = (u16*)(ws + WL1_OFF);
  u16* wlin = (u16*)(ws + WLIN_OFF);
  u16* h0buf = (u16*)(ws + H0_OFF);
  u16* h1buf = (u16*)(ws + H1_OFF);
  u32* bars = (u32*)(ws + BAR_OFF);

  hipMemsetAsync(ws + BAR_OFF, 0, 2048, stream);
  const int NTOT = 2048 * 512 + 128 * 2048 + 2048 * 1024 + 128 * 512;
  prep_kernel<<<dim3((NTOT + 255) / 256), dim3(256), 0, stream>>>(
      wih0, whh0, wih1, whh1, wlinf, wl0a, wl0b, wl1, wlin);
  lstm_kernel<<<dim3(NWG), dim3(256), LDS_BYTES, stream>>>(
      bih0, bhh0, bih1, bhh1, blin, z, nfr, wl0a, wl0b, wl1, wlin, h0buf, h1buf, bars, out);
}

// Round 14
// 7018.099 us; speedup vs baseline: 1.7135x; 1.0807x over previous
//
#include <hip/hip_runtime.h>

#define TT 800

typedef __attribute__((ext_vector_type(8))) short bf16x8;
typedef __attribute__((ext_vector_type(4))) float f32x4;
typedef __attribute__((ext_vector_type(2))) unsigned long long u64x2;
typedef unsigned short u16;
typedef unsigned int u32;
typedef unsigned long long u64;

constexpr int NWG = 136, RT = 32;
constexpr size_t WL0A_OFF = 0;              // [2048][512] bf16 (W_hh0, K-major)
constexpr size_t WL0B_OFF = 2097152;        // [128][2048] bf16 (W_ih0^T row-gather)
constexpr size_t WL1_OFF  = 2621440;        // [2048][1024] bf16
constexpr size_t WLIN_OFF = 6815744;        // [128][512] bf16
constexpr size_t H0_OFF   = 6946816;        // [2][256][512] bf16
constexpr size_t H1_OFF   = 7471104;        // [2][256][512] bf16
constexpr size_t BAR_OFF  = 7995392;        // flag words(1KB) + handshake (2KB memset)
constexpr int HB = 256 * 512;
// ROUND-14 LDS (double-buffered; >64KB opt-in proven in r7/r10):
//   A  (h0) 32 x 520 u16 = 33280 @ 0
//   A2 (h1) 32 x 520 u16 = 33280 @ 33280
//   Gf0 (L0 gates) 32 x 129 f32 = 16512 @ 66560
//   Gf1 (L1 gates) 32 x 129 f32 = 16512 @ 83072
//   P (softmax) 3 x 256 f32 = 3072 @ 99584  -> 102656 (<160K/CU, 1 WG/CU)
constexpr int A_ST = 520;
constexpr int A2_OFF_B = 33280;
constexpr int G0_OFF_B = 66560;
constexpr int G1_OFF_B = 83072;
constexpr int P_OFF_B  = 99584;
constexpr int LDS_BYTES = 102656;

__device__ __forceinline__ u16 f2b(float x) {
  u32 u = __float_as_uint(x);
  return (u16)((u + 0x7FFFu + ((u >> 16) & 1u)) >> 16);   // RNE fp32->bf16
}
__device__ __forceinline__ float b2f(u16 v) { return __uint_as_float(((u32)v) << 16); }
__device__ __forceinline__ float sigf(float x) { return 1.f / (1.f + __expf(-x)); }
__device__ __forceinline__ float tanh_f(float x) { float e = __expf(2.f * x); return 1.f - 2.f / (e + 1.f); }

// ---- agent-scope (cross-XCD safe) data ops: fallback path ----
__device__ __forceinline__ u64 ld_coh8(const u64* p) {
  return __hip_atomic_load(p, __ATOMIC_RELAXED, __HIP_MEMORY_SCOPE_AGENT);
}
__device__ __forceinline__ void st_coh8(u64* p, u64 v) {
  __hip_atomic_store(p, v, __ATOMIC_RELAXED, __HIP_MEMORY_SCOPE_AGENT);
}
// ---- Flag transport (round-9 champion, UNCHANGED): per-WG flag words,
// plain posted store after the B-drain; waiter = lanes 0..16 of wave 0,
// one coalesced read + __all, buffer_inv per retry (lok) / agent+sleep.
__device__ __forceinline__ void fpost_l(u32* fw, u32 v) { *(volatile u32*)fw = v; }
__device__ __forceinline__ void fpost_a(u32* fw, u32 v) {
  __hip_atomic_store(fw, v, __ATOMIC_RELAXED, __HIP_MEMORY_SCOPE_AGENT);
}
__device__ __forceinline__ void wave_poll(u32* Fw, int lane, u32 thr, bool lok) {
  int idx = (lane < 17) ? lane : 16;
  if (lok) {
    while (true) {
      u32 v = *(volatile u32*)(Fw + idx);
      if (__all((int)(v >= thr))) break;
      asm volatile("buffer_inv" ::: "memory");
    }
  } else {
    while (true) {
      u32 v = __hip_atomic_load(Fw + idx, __ATOMIC_RELAXED, __HIP_MEMORY_SCOPE_AGENT);
      if (__all((int)(v >= thr))) break;
      __builtin_amdgcn_s_sleep(1);
    }
  }
}
__device__ __forceinline__ void l1inv() { asm volatile("buffer_inv" ::: "memory"); }

__global__ void prep_kernel(const float* __restrict__ wih0, const float* __restrict__ whh0,
                            const float* __restrict__ wih1, const float* __restrict__ whh1,
                            const float* __restrict__ wlinf,
                            u16* __restrict__ wl0a, u16* __restrict__ wl0b,
                            u16* __restrict__ wl1, u16* __restrict__ wlin) {
  int i = blockIdx.x * 256 + threadIdx.x;
  const int NA = 2048 * 512, NB = 128 * 2048, N1 = 2048 * 1024, N2 = 128 * 512;
  if (i < NA) {
    int col = i >> 9, k = i & 511;
    wl0a[i] = f2b(whh0[col * 512 + k]);
  } else if (i < NA + NB) {
    int j = i - NA, k = j >> 11, col = j & 2047;
    wl0b[j] = f2b(wih0[col * 128 + k]);
  } else if (i < NA + NB + N1) {
    int j = i - NA - NB, col = j >> 10, k = j & 1023;
    float v = (k < 512) ? wih1[col * 512 + k] : whh1[col * 512 + (k - 512)];
    wl1[j] = f2b(v);
  } else if (i < NA + NB + N1 + N2) {
    int j = i - NA - NB - N1, col = j >> 9, k = j & 511;
    wlin[j] = f2b(wlinf[col * 512 + k]);
  }
}

// 136 persistent WGs, XCD-local tiles (tile = bid&7, slot w = bid>>3),
// runtime-verified via XCC_ID handshake (agent fallback if not co-XCD).
// Protocol (unchanged): tick tau consumes h0(tau-1) [slot (tau-1)&1] and
// h1(tau-2) [slot tau&1]; produces h0(tau) [slot tau&1], h1(tau-1)
// [slot (tau+1)&1]. Gate: all 17 flag words >= tau+1.
//
// ROUND-14: ISOLATED B4/B5 REMOVAL (the one untested single variable).
// Round-10 bundled this with per-wave flags + all-wave polling and
// regressed; attribution (poll thrash) unverified. Here: champion flag
// transport + wave-0 poll + __syncthreads, ONLY the LDS double-buffer
// (A2 for h1, Gf1 for L1 gates) so the tick becomes 5 sync events:
//   poll -> B1 -> stage h0->A AND h1->A2 (all consumed before B2, zero
//   live-across-MFMA regs) -> B2 -> 192 MFMA (L0+L1p1 from A, L1p2 from
//   A2) -> Gf0/Gf1 -> B3 -> cell0 (verbatim champion gather) + cell1 ->
//   B6(drain) -> post.
// Champion's h1 loads issued "in flight" before B2/B4 were ALWAYS
// drained by those barriers' implicit vmcnt(0) — no overlap is lost by
// consuming them into A2 up front.
__global__ __launch_bounds__(256, 1) void lstm_kernel(
    const float* __restrict__ bih0, const float* __restrict__ bhh0,
    const float* __restrict__ bih1, const float* __restrict__ bhh1,
    const float* __restrict__ blin,
    const int* __restrict__ z, const int* __restrict__ nfr,
    const u16* __restrict__ wl0a, const u16* __restrict__ wl0b,
    const u16* __restrict__ wl1, const u16* __restrict__ wlin,
    u16* __restrict__ h0buf, u16* __restrict__ h1buf,
    u32* __restrict__ bars, float* __restrict__ out) {
  extern __shared__ char smem[];
  u16* A  = (u16*)smem;
  u16* A2 = (u16*)(smem + A2_OFF_B);
  float* Gf0 = (float*)(smem + G0_OFF_B);
  float* Gf1 = (float*)(smem + G1_OFF_B);
  float* Pm = (float*)(smem + P_OFF_B);
  float* Ps = Pm + 256;
  float* Pt = Ps + 256;
  const int wg = blockIdx.x;
  const int w_all = wg >> 3;            // slot on the XCD: 0..16
  const bool isC = (w_all < 16);
  const int tile = wg & 7;              // XCD id; all 17 WGs of a tile co-XCD
  const int w = isC ? w_all : 16;
  const int slot = isC ? w : 16;        // flag-word slot
  const int tid = threadIdx.x, lane = tid & 63, wv = tid >> 6;
  const int l15 = lane & 15, l4 = lane >> 4;
  const int row0 = tile * RT;
  u32* Fw = bars + tile * 32;           // 17 words in one 128B line
  const f32x4 VZ = {0.f, 0.f, 0.f, 0.f};
  // cell-phase mapping: thread -> (row rC, 4 consecutive units u0C..+3)
  const int rC = tid >> 3, u0C = (tid & 7) * 4;
  // logits softmax mapping
  const int cuL = tid & 31, rgL = tid >> 5;

  float c0s[4] = {0, 0, 0, 0}, c1s[4] = {0, 0, 0, 0};
  float accN = 0.f, nflv = 0.f;
  float bias0c[2], bias1c[2], biasLc[2];
  bf16x8 bq0R[32];                  // L0 W_hh0: 2 cb x 16 kb = 128 reg
  bf16x8 bq1R[64];                  // L1: 2 cb x 32 kb = 256 reg (AGPR)
  bf16x8 wlR[32];                   // logits: 2 cb x 16 kb (disjoint liveness)

  if (isC) {
#pragma unroll
    for (int cb = 0; cb < 2; ++cb) {
      int col = wv * 512 + w * 32 + cb * 16 + l15;   // gate wv, half cb
      bias0c[cb] = bih0[col] + bhh0[col];
      bias1c[cb] = bih1[col] + bhh1[col];
      const u16* b0 = wl0a + (size_t)col * 512 + l4 * 8;
#pragma unroll
      for (int kb = 0; kb < 16; ++kb) bq0R[cb * 16 + kb] = *(const bf16x8*)(b0 + kb * 32);
      const u16* b1 = wl1 + (size_t)col * 1024 + l4 * 8;
#pragma unroll
      for (int kb = 0; kb < 32; ++kb) bq1R[cb * 32 + kb] = *(const bf16x8*)(b1 + kb * 32);
    }
  } else {
#pragma unroll
    for (int cb = 0; cb < 2; ++cb) {
      int colV = wv * 32 + cb * 16 + l15;
      biasLc[cb] = blin[colV];
      const u16* bL = wlin + (size_t)colV * 512 + l4 * 8;
#pragma unroll
      for (int kb = 0; kb < 16; ++kb) wlR[cb * 16 + kb] = *(const bf16x8*)(bL + kb * 32);
    }
    if (rgL == 0) nflv = (float)nfr[row0 + cuL];
  }

  // ---- one-time XCD co-residency handshake (agent scope, off hot path) ----
  // bars layout: [0..255] per-tile flag words (tile*32 + slot);
  // [256..263] per-tile XCD masks; [272] grid init counter. All in 2KB memset.
  u32 xcc;
  asm volatile("s_getreg_b32 %0, hwreg(HW_REG_XCC_ID)" : "=s"(xcc));
  {
    int* hls = (int*)Pm;       // LDS broadcast slot (Pm unused until loop)
    if (tid == 0) {
      u32 bit = 1u << (xcc & 31u);
      __hip_atomic_fetch_or(bars + 256 + tile, bit, __ATOMIC_RELAXED, __HIP_MEMORY_SCOPE_AGENT);
      __hip_atomic_fetch_add(bars + 272, 1u, __ATOMIC_RELAXED, __HIP_MEMORY_SCOPE_AGENT);
      while (__hip_atomic_load(bars + 272, __ATOMIC_RELAXED, __HIP_MEMORY_SCOPE_AGENT) < (u32)NWG)
        __builtin_amdgcn_s_sleep(1);
      u32 m = __hip_atomic_load(bars + 256 + tile, __ATOMIC_RELAXED, __HIP_MEMORY_SCOPE_AGENT);
      hls[0] = (m == bit) ? 1 : 0;
    }
    __syncthreads();
    const_cast<volatile int&>(hls[0]);
  }
  const bool lok = (((volatile int*)Pm)[0] != 0);
  __syncthreads();   // everyone has read hls[0]; Pm free for reuse

  if (isC && w == 0) {
    u64* z0 = (u64*)(h0buf + HB + row0 * 512);
    u64* z1 = (u64*)(h1buf + row0 * 512);
    u64* z2 = (u64*)(h1buf + HB + row0 * 512);
    if (lok) {
      for (int k = tid; k < 2048; k += 256) { z0[k] = 0; z1[k] = 0; z2[k] = 0; }
    } else {
      for (int k = tid; k < 2048; k += 256) { st_coh8(z0 + k, 0); st_coh8(z1 + k, 0); st_coh8(z2 + k, 0); }
    }
  }
  __syncthreads();   // full drain: init stores visible before the flag init
  if (tid == 0) { if (lok) fpost_l(Fw + slot, 1u); else fpost_a(Fw + slot, 1u); }

  auto ldA = [&](int rb, int kb) {
    return *(const bf16x8*)(A + (rb * 16 + l15) * A_ST + kb * 32 + l4 * 8);
  };
  auto ldA2 = [&](int rb, int kb) {
    return *(const bf16x8*)(A2 + (rb * 16 + l15) * A_ST + kb * 32 + l4 * 8);
  };

#pragma unroll 1
  for (int tau = 0; tau <= TT + 1; ++tau) {
    if (wv == 0) wave_poll(Fw, lane, (u32)(tau + 1), lok);
    __syncthreads();  // B1: tick inputs published
    if (lok) l1inv();  // drop stale h lines from this CU's L1
    const u16* h0src = h0buf + ((tau + 1) & 1) * HB + row0 * 512;
    const u64* h1s64 = (const u64*)(h1buf + (tau & 1) * HB + row0 * 512);
    const bool l0act = isC && (tau < TT);
    const bool l1act = isC && (tau >= 1 && tau <= TT);

    if (isC) {
      // ---- stage h0(tau-1)->A (8x16B) and h1(tau-2)->A2 (8x16B) ----
      if (tau <= TT) {
        u64x2 tv[8];
        const u64* s64 = (const u64*)h0src;
        if (lok) {
#pragma unroll
          for (int c = 0; c < 8; ++c) tv[c] = *(const u64x2*)(s64 + (c * 256 + tid) * 2);
        } else {
#pragma unroll
          for (int c = 0; c < 8; ++c) {
            int li = c * 256 + tid;
            tv[c][0] = ld_coh8(s64 + li * 2); tv[c][1] = ld_coh8(s64 + li * 2 + 1);
          }
        }
#pragma unroll
        for (int c = 0; c < 8; ++c) {
          int li = c * 256 + tid, row = li >> 6, cc = li & 63;
          *(u64x2*)(A + row * A_ST + cc * 8) = tv[c];
        }
      }
      if (l1act) {
        u64x2 hv[8];
        if (lok) {
#pragma unroll
          for (int c = 0; c < 8; ++c) hv[c] = *(const u64x2*)(h1s64 + (c * 256 + tid) * 2);
        } else {
#pragma unroll
          for (int c = 0; c < 8; ++c) {
            int li = c * 256 + tid;
            hv[c][0] = ld_coh8(h1s64 + li * 2); hv[c][1] = ld_coh8(h1s64 + li * 2 + 1);
          }
        }
#pragma unroll
        for (int c = 0; c < 8; ++c) {
          int li = c * 256 + tid, row = li >> 6, cc = li & 63;
          *(u64x2*)(A2 + row * A_ST + cc * 8) = hv[c];
        }
      }
      __syncthreads();  // B2: A + A2 ready (all staging regs dead here)

      f32x4 acc0[2][2] = {{VZ, VZ}, {VZ, VZ}};
      f32x4 acc1[2][2] = {{VZ, VZ}, {VZ, VZ}};
      if (l0act) {
#pragma unroll
        for (int kb = 0; kb < 16; ++kb) {
          bf16x8 a0 = ldA(0, kb), a1 = ldA(1, kb);
#pragma unroll
          for (int cb = 0; cb < 2; ++cb) {
            acc0[0][cb] = __builtin_amdgcn_mfma_f32_16x16x32_bf16(a0, bq0R[cb * 16 + kb], acc0[0][cb], 0, 0, 0);
            acc0[1][cb] = __builtin_amdgcn_mfma_f32_16x16x32_bf16(a1, bq0R[cb * 16 + kb], acc0[1][cb], 0, 0, 0);
          }
        }
      }
      if (l1act) {
        // L1 part 1: K 0..511 (h0(tau-1)) from A
#pragma unroll
        for (int kb = 0; kb < 16; ++kb) {
          bf16x8 a0 = ldA(0, kb), a1 = ldA(1, kb);
#pragma unroll
          for (int cb = 0; cb < 2; ++cb) {
            acc1[0][cb] = __builtin_amdgcn_mfma_f32_16x16x32_bf16(a0, bq1R[cb * 32 + kb], acc1[0][cb], 0, 0, 0);
            acc1[1][cb] = __builtin_amdgcn_mfma_f32_16x16x32_bf16(a1, bq1R[cb * 32 + kb], acc1[1][cb], 0, 0, 0);
          }
        }
        // L1 part 2: K 512..1023 (h1(tau-2)) from A2
#pragma unroll
        for (int kb = 16; kb < 32; ++kb) {
          bf16x8 a0 = ldA2(0, kb - 16), a1 = ldA2(1, kb - 16);
#pragma unroll
          for (int cb = 0; cb < 2; ++cb) {
            acc1[0][cb] = __builtin_amdgcn_mfma_f32_16x16x32_bf16(a0, bq1R[cb * 32 + kb], acc1[0][cb], 0, 0, 0);
            acc1[1][cb] = __builtin_amdgcn_mfma_f32_16x16x32_bf16(a1, bq1R[cb * 32 + kb], acc1[1][cb], 0, 0, 0);
          }
        }
      }
      if (l0act) {
#pragma unroll
        for (int rb = 0; rb < 2; ++rb)
#pragma unroll
          for (int cb = 0; cb < 2; ++cb)
#pragma unroll
            for (int q = 0; q < 4; ++q)
              Gf0[(rb * 16 + l4 * 4 + q) * 129 + wv * 32 + cb * 16 + l15] = acc0[rb][cb][q] + bias0c[cb];
      }
      if (l1act) {
#pragma unroll
        for (int rb = 0; rb < 2; ++rb)
#pragma unroll
          for (int cb = 0; cb < 2; ++cb)
#pragma unroll
            for (int q = 0; q < 4; ++q)
              Gf1[(rb * 16 + l4 * 4 + q) * 129 + wv * 32 + cb * 16 + l15] = acc1[rb][cb][q] + bias1c[cb];
      }
      __syncthreads();  // B3: Gf0+Gf1 ready AND all A/A2 ds-reads done

      if (l0act) {
        // ---- cell0: gates + W_ih0 gather + c/h update (verbatim champion) ----
        float g4[4][4];
#pragma unroll
        for (int g = 0; g < 4; ++g)
#pragma unroll
          for (int j = 0; j < 4; ++j) g4[g][j] = Gf0[rC * 129 + g * 32 + u0C + j];
        if (tau >= 1) {
          int zr = z[(row0 + rC) * TT + (tau - 1)];
          const u16* gb = wl0b + (size_t)zr * 2048 + w * 32 + u0C;
#pragma unroll
          for (int g = 0; g < 4; ++g) {
            u64 v = *(const u64*)(gb + g * 512);
#pragma unroll
            for (int j = 0; j < 4; ++j) g4[g][j] += b2f((u16)(v >> (16 * j)));
          }
        }
        u64 pk = 0;
#pragma unroll
        for (int j = 0; j < 4; ++j) {
          float cn = sigf(g4[1][j]) * c0s[j] + sigf(g4[0][j]) * tanh_f(g4[2][j]);
          float hn = sigf(g4[3][j]) * tanh_f(cn);
          c0s[j] = cn;
          pk |= ((u64)f2b(hn)) << (16 * j);
        }
        u16* h0w = h0buf + (tau & 1) * HB + row0 * 512;
        u64* dst = (u64*)(h0w + rC * 512 + w * 32 + u0C);
        if (lok) *dst = pk; else st_coh8(dst, pk);   // ack rides under cell1
      }
      if (l1act) {
        // ---- cell1 ----
        float g4[4][4];
#pragma unroll
        for (int g = 0; g < 4; ++g)
#pragma unroll
          for (int j = 0; j < 4; ++j) g4[g][j] = Gf1[rC * 129 + g * 32 + u0C + j];
        u64 pk = 0;
#pragma unroll
        for (int j = 0; j < 4; ++j) {
          float cn = sigf(g4[1][j]) * c1s[j] + sigf(g4[0][j]) * tanh_f(g4[2][j]);
          float hn = sigf(g4[3][j]) * tanh_f(cn);
          c1s[j] = cn;
          pk |= ((u64)f2b(hn)) << (16 * j);
        }
        u16* h1w = h1buf + ((tau + 1) & 1) * HB + row0 * 512;
        u64* dst = (u64*)(h1w + rC * 512 + w * 32 + u0C);
        if (lok) *dst = pk; else st_coh8(dst, pk);
      }
      __syncthreads();  // B6: vmcnt(0) drain => h0+h1 stores visible BEFORE flag
      if (tid == 0) { if (lok) fpost_l(Fw + slot, (u32)(tau + 2)); else fpost_a(Fw + slot, (u32)(tau + 2)); }
    } else {
      // ---------------- logits WG: NLL(tau-2) (unchanged) ----------------
      const bool lgact = (tau >= 2);
      if (lgact) {
        u64x2 tv[8];
        if (lok) {
#pragma unroll
          for (int c = 0; c < 8; ++c) tv[c] = *(const u64x2*)(h1s64 + (c * 256 + tid) * 2);
        } else {
#pragma unroll
          for (int c = 0; c < 8; ++c) {
            int li = c * 256 + tid;
            tv[c][0] = ld_coh8(h1s64 + li * 2); tv[c][1] = ld_coh8(h1s64 + li * 2 + 1);
          }
        }
#pragma unroll
        for (int c = 0; c < 8; ++c) {
          int li = c * 256 + tid, row = li >> 6, cc = li & 63;
          *(u64x2*)(A + row * A_ST + cc * 8) = tv[c];
        }
      }
      __syncthreads();  // B2: staged (loads retired)
      if (tid == 0) { if (lok) fpost_l(Fw + slot, (u32)(tau + 2)); else fpost_a(Fw + slot, (u32)(tau + 2)); }  // early release
      if (lgact) {
        f32x4 accL[2][2] = {{VZ, VZ}, {VZ, VZ}};
#pragma unroll
        for (int kb = 0; kb < 16; ++kb) {
          bf16x8 a0 = ldA(0, kb), a1 = ldA(1, kb);
#pragma unroll
          for (int cb = 0; cb < 2; ++cb) {
            accL[0][cb] = __builtin_amdgcn_mfma_f32_16x16x32_bf16(a0, wlR[cb * 16 + kb], accL[0][cb], 0, 0, 0);
            accL[1][cb] = __builtin_amdgcn_mfma_f32_16x16x32_bf16(a1, wlR[cb * 16 + kb], accL[1][cb], 0, 0, 0);
          }
        }
#pragma unroll
        for (int rb = 0; rb < 2; ++rb)
#pragma unroll
          for (int cb = 0; cb < 2; ++cb)
#pragma unroll
            for (int q = 0; q < 4; ++q)
              Gf0[(rb * 16 + l4 * 4 + q) * 129 + wv * 32 + cb * 16 + l15] = accL[rb][cb][q] + biasLc[cb];
      }
      __syncthreads();  // B3: Gf ready
      if (lgact) {
        int t2 = tau - 2;
        int r = cuL, k = rgL;            // 8 threads per row x 16 cols
        float vloc[16], mloc = -3.4e38f;
#pragma unroll
        for (int j = 0; j < 16; ++j) {
          vloc[j] = Gf0[r * 129 + k * 16 + j];
          mloc = fmaxf(mloc, vloc[j]);
        }
        Pm[r * 8 + k] = mloc;
        __syncthreads();
        float mrow = Pm[r * 8];
#pragma unroll
        for (int j = 1; j < 8; ++j) mrow = fmaxf(mrow, Pm[r * 8 + j]);
        int zr = z[(row0 + r) * TT + t2];
        float sloc = 0.f, tloc = 0.f;
#pragma unroll
        for (int j = 0; j < 16; ++j) {
          sloc += __expf(vloc[j] - mrow);
          tloc += (k * 16 + j == zr) ? vloc[j] : 0.f;
        }
        Ps[r * 8 + k] = sloc; Pt[r * 8 + k] = tloc;
        __syncthreads();
        if (k == 0) {
          float s = 0.f, tv2 = 0.f;
#pragma unroll
          for (int j = 0; j < 8; ++j) { s += Ps[r * 8 + j]; tv2 += Pt[r * 8 + j]; }
          if ((float)t2 < nflv) accN += mrow + __logf(s) - tv2;
        }
      } else {
        __syncthreads(); __syncthreads();
      }
    }
  }

  if (!isC && rgL == 0) out[row0 + cuL] = accN * (1.0f / TT);
}

extern "C" void kernel_launch(void* const* d_in, const int* in_sizes, int n_in,
                              void* d_out, int out_size, void* d_ws, size_t ws_size,
                              hipStream_t stream) {
  const float* wih0 = (const float*)d_in[0];
  const float* whh0 = (const float*)d_in[1];
  const float* bih0 = (const float*)d_in[2];
  const float* bhh0 = (const float*)d_in[3];
  const float* wih1 = (const float*)d_in[4];
  const float* whh1 = (const float*)d_in[5];
  const float* bih1 = (const float*)d_in[6];
  const float* bhh1 = (const float*)d_in[7];
  const float* wlinf = (const float*)d_in[8];
  const float* blin = (const float*)d_in[9];
  const int* z = (const int*)d_in[10];
  const int* nfr = (const int*)d_in[11];
  float* out = (float*)d_out;
  char* ws = (char*)d_ws;
  u16* wl0a = (u16*)(ws + WL0A_OFF);
  u16* wl0b = (u16*)(ws + WL0B_OFF);
  u16* wl1 = (u16*)(ws + WL1_OFF);
  u16* wlin = (u16*)(ws + WLIN_OFF);
  u16* h0buf = (u16*)(ws + H0_OFF);
  u16* h1buf = (u16*)(ws + H1_OFF);
  u32* bars = (u32*)(ws + BAR_OFF);

  // >64KB dynamic LDS opt-in (160KB/CU on gfx950); host-side, set once.
  static bool attr_set = false;
  if (!attr_set) {
    hipFuncSetAttribute(reinterpret_cast<const void*>(lstm_kernel),
                        hipFuncAttributeMaxDynamicSharedMemorySize, LDS_BYTES);
    attr_set = true;
  }

  hipMemsetAsync(ws + BAR_OFF, 0, 2048, stream);
  const int NTOT = 2048 * 512 + 128 * 2048 + 2048 * 1024 + 128 * 512;
  prep_kernel<<<dim3((NTOT + 255) / 256), dim3(256), 0, stream>>>(
      wih0, whh0, wih1, whh1, wlinf, wl0a, wl0b, wl1, wlin);
  lstm_kernel<<<dim3(NWG), dim3(256), LDS_BYTES, stream>>>(
      bih0, bhh0, bih1, bhh1, blin, z, nfr, wl0a, wl0b, wl1, wlin, h0buf, h1buf, bars, out);
}